// Round 10
// baseline (220.744 us; speedup 1.0000x reference)
//
#include <hip/hip_runtime.h>

// y[e] = W2 . relu(W1 . concat(z[src[e]], z[dst[e]]) + b1) + b2
// N=50000, D=128, H=512, E=500000. 131 GFLOP in GEMM1.
// R17: R15 base (121.6us; R16's H-split/2-block regressed: doubled gather
// traffic, dead end) + three LDS-ledger edits:
//  1. w2 -> 32 regs (loop-invariant; was 8 LDS reads/wave/tile).
//  2. acc ZERO-init + b1 applied in epilogue: b1's 8 reads move into the
//     fence-free body (compiler schedules them across the kst loop instead
//     of blocking kst0 after the barrier); init becomes VALU.
//  3. gather issue at TOP of tile (was mid): prefetch slack half-tile ->
//     ~full tile; kst 0..15 one uninterrupted MFMA cluster. vmcnt ledger
//     unchanged: [4 G][4 idx][2 atomics] -> vmcnt(6). dbuf-safe: the buf
//     being written was last read before the barrier just passed (LDS read
//     latency ~120cy << barrier + vmem writeback).
// Conflict counter forensics (R12/R16): 8.0M tracks A-READ instr count
// (R12 2x reads -> 16M; R16 2x gather-writes, same reads -> 8M) -> it's
// the A-read b128 pattern, folded into the ~12cyc/b128 throughput. Benign.
// Kept: persistent blocks (grid=256), W1-in-regs (128/wave), 32x32x16
// operand-swapped MFMA (C row=h col=edge), source-side XOR swizzle,
// atomic epilogue into b2-prefilled out, single barrier/tile.

typedef __bf16 bf16x8 __attribute__((ext_vector_type(8)));
typedef float f32x4  __attribute__((ext_vector_type(4)));
typedef float f32x16 __attribute__((ext_vector_type(16)));

__device__ __forceinline__ unsigned short f2b(float f) {
    unsigned int u = __float_as_uint(f);
    u = (u + 0x7fffu + ((u >> 16) & 1u)) >> 16;   // RNE
    return (unsigned short)u;
}

__device__ __forceinline__ void gload_lds16(const unsigned short* g, unsigned short* l) {
    __builtin_amdgcn_global_load_lds(
        (const __attribute__((address_space(1))) unsigned int*)g,
        (__attribute__((address_space(3))) unsigned int*)l, 16, 0, 0);
}

// zb: z as bf16 [N][128].  w1s: W1 in 32x32x16 A-fragment order:
// w1s[(hb*16 + kst)*512 + lane*8 + t]
//   = bf16(W1[hb*32 + (lane&31)][kst*16 + (lane>>5)*8 + t]),  hb,kst in 0..15
// Also pre-fills out[] with b2 (atomicAdd target).
__global__ void prep_kernel(const float* __restrict__ z, const float* __restrict__ W1,
                            const float* __restrict__ b2p,
                            unsigned short* __restrict__ zb, unsigned short* __restrict__ w1s,
                            float* __restrict__ outz, int nz4, int nout4) {
    int stride = gridDim.x * blockDim.x;
    const int nw = 256 * 64;   // (hb*16+kst) x lane
    const int total = nz4 + nw + nout4;
    const float b2v = b2p[0];
    for (int idx = blockIdx.x * blockDim.x + threadIdx.x; idx < total; idx += stride) {
        if (idx < nz4) {
            float4 v = ((const float4*)z)[idx];
            ushort4 o;
            o.x = f2b(v.x); o.y = f2b(v.y); o.z = f2b(v.z); o.w = f2b(v.w);
            ((ushort4*)zb)[idx] = o;
        } else if (idx < nz4 + nw) {
            int u = idx - nz4;            // 0..16383
            int lane = u & 63;
            int blk  = u >> 6;            // hb*16 + kst
            int h  = (blk >> 4) * 32 + (lane & 31);
            int kb = (blk & 15) * 16 + (lane >> 5) * 8;
            const float* src = W1 + h * 256 + kb;
            ushort4 o0, o1;
            float4 v0 = *(const float4*)(src);
            float4 v1 = *(const float4*)(src + 4);
            o0.x = f2b(v0.x); o0.y = f2b(v0.y); o0.z = f2b(v0.z); o0.w = f2b(v0.w);
            o1.x = f2b(v1.x); o1.y = f2b(v1.y); o1.z = f2b(v1.z); o1.w = f2b(v1.w);
            ushort4* dst = (ushort4*)(w1s + u * 8);
            dst[0] = o0; dst[1] = o1;
        } else {
            ((float4*)outz)[idx - nz4 - nw] = (float4){b2v, b2v, b2v, b2v};
        }
    }
}

__global__ __launch_bounds__(512, 2)
void edge_mlp_kernel(const int* __restrict__ ei, const unsigned short* __restrict__ zb,
                     const unsigned short* __restrict__ w1s,
                     const float* __restrict__ b1, const float* __restrict__ W2,
                     float* __restrict__ out, int E, int ntiles) {
    __shared__ unsigned short ldsA[2][64 * 256];  // 64 KB, dbuf A tiles
    __shared__ float ldsB1[512];                  // 2 KB staged b1

    const int tid  = threadIdx.x;
    const int lane = tid & 63;
    const int w    = tid >> 6;        // 0..7 : 64-h slice of H=512
    const int l31  = lane & 31;
    const int hi   = lane >> 5;       // 0/1 : k-half within frag, C row-group
    const int G    = gridDim.x;
    const int t0   = blockIdx.x;
    if (t0 >= ntiles) return;

    ldsB1[tid] = b1[tid];

    // ---- persistent W1: wave w holds hb w*2, w*2+1 (64 h), in regs ----
    uint4 breg[2][16];                // 128 regs
    #pragma unroll
    for (int j = 0; j < 2; ++j)
        #pragma unroll
        for (int kst = 0; kst < 16; ++kst)
            breg[j][kst] = *(const uint4*)(w1s + (((w * 2 + j) * 16 + kst) << 9) + lane * 8);

    // ---- w2 hoisted: lane holds its (j,q,hi) slice, 32 regs ----
    f32x4 w2r[2][4];
    #pragma unroll
    for (int j = 0; j < 2; ++j)
        #pragma unroll
        for (int q = 0; q < 4; ++q)
            w2r[j][q] = *(const f32x4*)&W2[w * 64 + j * 32 + q * 8 + hi * 4];

    // gather: instr q covers rows m=(w*8+q*2)+hi; lane L writes LDS slot
    // L&31 of the row pair; source k-slot pre-swizzled: side*16 + (l15^(m&7)).
    const int side = (lane >> 4) & 1;
    const int l15  = lane & 15;
    const int swz3 = (l31 & 7) << 3;  // read-side XOR on the low-4 slot bits (x8 elems)

#define ISSUE_GATHER(BUF)                                                     \
    do {                                                                      \
        _Pragma("unroll")                                                     \
        for (int q_ = 0; q_ < 4; ++q_) {                                      \
            int m_   = w * 8 + q_ * 2 + hi;                                   \
            int s15_ = l15 ^ (m_ & 7);                                        \
            gload_lds16(zb + (((long)ival[q_]) << 7) + (s15_ << 3),           \
                        &ldsA[BUF][(w * 8 + q_ * 2) << 8]);                   \
        }                                                                     \
    } while (0)

    // drain staging loads (breg/w2/b1) so the vmcnt ledger starts clean
    asm volatile("s_waitcnt vmcnt(0) lgkmcnt(0)" ::: "memory");

    // ---- prologue: idx(T0) -> gather(T0) -> idx(T1) -> 2 zero-atomics ----
    int ival[4];
    #pragma unroll
    for (int q = 0; q < 4; ++q) {
        int e = t0 * 64 + w * 8 + q * 2 + hi;
        e = (e < E) ? e : (E - 1);
        ival[q] = ei[side * E + e];
    }
    ISSUE_GATHER(0);
    asm volatile("" ::: "memory");     // pin: idx(T1) stays AFTER gathers
    {
        int t1 = t0 + G;
        #pragma unroll
        for (int q = 0; q < 4; ++q) {
            int e = t1 * 64 + w * 8 + q * 2 + hi;
            e = (e < E) ? e : (E - 1);
            ival[q] = ei[side * E + e];
        }
    }
    asm volatile("" ::: "memory");     // pin: zero-atomics AFTER idx(T1)
    if (hi == 0) {                     // 2 queue-padding atomics (add 0.0f)
        atomicAdd(&out[t0 * 64 + l31], 0.0f);
        atomicAdd(&out[t0 * 64 + 32 + l31], 0.0f);
    }

    int cur = 0;
    for (int t = t0; t < ntiles; t += G) {
        // own 4 gathers are oldest; 4 idx + 2 atomics are newer -> vmcnt(6)
        asm volatile("s_waitcnt vmcnt(6)" ::: "memory");
        __builtin_amdgcn_s_barrier();
        asm volatile("" ::: "memory");

        // top-issue: gathers for tile t+1 into the buffer freed before the
        // barrier we just passed. Full-tile prefetch slack.
        ISSUE_GATHER(cur ^ 1);
        asm volatile("" ::: "memory");  // pin: idx(t+2) AFTER gathers
        {
            int tt = t + 2 * G;
            #pragma unroll
            for (int q = 0; q < 4; ++q) {
                int e = tt * 64 + w * 8 + q * 2 + hi;
                e = (e < E) ? e : (E - 1);
                ival[q] = ei[side * E + e];
            }
        }
        asm volatile("" ::: "memory");  // pin: body mem ops AFTER idx

        const unsigned short* bufc = &ldsA[cur][0];

        // acc ZERO-init (VALU; b1 applied in epilogue). C row=h, col=edge.
        f32x16 acc[2][2];                 // [edge-blk i][h-blk j]
        #pragma unroll
        for (int i = 0; i < 2; ++i)
            #pragma unroll
            for (int j = 0; j < 2; ++j)
                #pragma unroll
                for (int r = 0; r < 16; ++r) acc[i][j][r] = 0.f;

        __builtin_amdgcn_s_setprio(1);
        #pragma unroll
        for (int kst = 0; kst < 16; ++kst) {
            bf16x8 a[2];
            #pragma unroll
            for (int i = 0; i < 2; ++i) {
                int s = kst * 2 + hi;     // logical 16B k-slot 0..31
                int off = ((i * 32 + l31) << 8) + ((s & 16) << 3) + (((s & 15) << 3) ^ swz3);
                a[i] = *(const bf16x8*)&bufc[off];
            }
            #pragma unroll
            for (int i = 0; i < 2; ++i)
                #pragma unroll
                for (int j = 0; j < 2; ++j)
                    acc[i][j] = __builtin_amdgcn_mfma_f32_32x32x16_bf16(
                        *(const bf16x8*)&breg[j][kst], a[i], acc[i][j], 0, 0, 0);
        }
        __builtin_amdgcn_s_setprio(0);

        // epilogue: y-partial = sum_h relu(acc + b1)*w2 ; b1 from LDS
        // (reads scheduleable across the body - no fence until atomics);
        // in-reg over (j,q,rr) + 1 shuffle (xor32); 2 atomics (hi==0).
        float s2[2];
        #pragma unroll
        for (int i = 0; i < 2; ++i) {
            float s = 0.f;
            #pragma unroll
            for (int j = 0; j < 2; ++j)
                #pragma unroll
                for (int q = 0; q < 4; ++q) {
                    f32x4 b1q = *(const f32x4*)&ldsB1[w * 64 + j * 32 + q * 8 + hi * 4];
                    #pragma unroll
                    for (int rr = 0; rr < 4; ++rr)
                        s = fmaf(fmaxf(acc[i][j][q * 4 + rr] + b1q[rr], 0.f),
                                 w2r[j][q][rr], s);
                }
            s += __shfl_xor(s, 32);
            s2[i] = s;
        }
        #pragma unroll
        for (int i = 0; i < 2; ++i) {
            int e = t * 64 + i * 32 + l31;
            if (hi == 0 && e < E) atomicAdd(&out[e], s2[i]);
        }

        cur ^= 1;
    }
#undef ISSUE_GATHER
}

extern "C" void kernel_launch(void* const* d_in, const int* in_sizes, int n_in,
                              void* d_out, int out_size, void* d_ws, size_t ws_size,
                              hipStream_t stream) {
    const float* z  = (const float*)d_in[0];
    const int*   ei = (const int*)d_in[1];
    const float* W1 = (const float*)d_in[2];
    const float* b1 = (const float*)d_in[3];
    const float* W2 = (const float*)d_in[4];
    const float* b2 = (const float*)d_in[5];
    float* out = (float*)d_out;

    const int E  = in_sizes[1] / 2;   // 500000
    const int NZ = in_sizes[0];       // 6400000 = N*D

    unsigned short* zb  = (unsigned short*)d_ws;       // 12.8 MB
    unsigned short* w1s = zb + NZ;                     // 256 KB (swizzled W1)

    prep_kernel<<<2048, 256, 0, stream>>>(z, W1, b2, zb, w1s, out, NZ / 4, E / 4);

    const int ntiles = (E + 63) / 64;                  // 7813
    int grid = 256;                                    // persistent, 1 block/CU
    edge_mlp_kernel<<<grid, 512, 0, stream>>>(ei, zb, w1s, b1, W2, out, E, ntiles);
}

// Round 12
// 206.133 us; speedup vs baseline: 1.0709x; 1.0709x over previous
//
#include <hip/hip_runtime.h>

// y[e] = W2 . relu(W1 . concat(z[src[e]], z[dst[e]]) + b1) + b2
// N=50000, D=128, H=512, E=500000. 131 GFLOP in GEMM1.
// R19: R18 with the pipeline off-by-one FIXED. R18 failed correctness:
// tile B reloaded idx(t+2G),idx(t+3G) - the tiles just gathered - instead
// of idx(t+4G),idx(t+5G) needed by the NEXT interval's mid-tile gathers
// (2-deep pipeline => prefetch distance 2 intervals = 4G/5G). Lesson:
// prefetch distances are pipeline-depth-dependent, re-derive on change.
// Structure (from R18): quad-buffered ldsA (4x32KB), 2-tile barrier
// interval: ONE vmcnt(10)+barrier per {tile A=t, tile B=t+G}. R13's
// barrier removal calibrated ~1-1.5K cyc/barrier incl correlated stalls;
// this halves the remaining one.
// Ledger/interval: [G_A'x4][epiA x2][G_B'x4][idx x8][epiB x2] -> newest
// 10 = 8 idx + 2 atomics -> vmcnt(10) completes G_A',G_B'. Prologue
// mirrors (8 gathers, 8 idx, 2 pad atomics). Tail tiles (tB >= ntiles)
// compute clamped garbage, atomics masked by e<E (final interval only).
// Kept verbatim from R15 (121.6us best): persistent blocks (grid=256),
// W1-in-regs (128/wave), 32x32x16 operand-swapped MFMA (C row=h col=edge),
// source-side XOR swizzle, MID-tile gather issue (load-bearing, 2x
// confirmed), b1 acc-init, w2 from LDS epilogue, atomic epilogue into
// b2-prefilled out. LDS 132KB -> 1 block/CU (grid=256 anyway).

typedef __bf16 bf16x8 __attribute__((ext_vector_type(8)));
typedef float f32x4  __attribute__((ext_vector_type(4)));
typedef float f32x16 __attribute__((ext_vector_type(16)));

__device__ __forceinline__ unsigned short f2b(float f) {
    unsigned int u = __float_as_uint(f);
    u = (u + 0x7fffu + ((u >> 16) & 1u)) >> 16;   // RNE
    return (unsigned short)u;
}

__device__ __forceinline__ void gload_lds16(const unsigned short* g, unsigned short* l) {
    __builtin_amdgcn_global_load_lds(
        (const __attribute__((address_space(1))) unsigned int*)g,
        (__attribute__((address_space(3))) unsigned int*)l, 16, 0, 0);
}

// zb: z as bf16 [N][128].  w1s: W1 in 32x32x16 A-fragment order:
// w1s[(hb*16 + kst)*512 + lane*8 + t]
//   = bf16(W1[hb*32 + (lane&31)][kst*16 + (lane>>5)*8 + t]),  hb,kst in 0..15
// Also pre-fills out[] with b2 (atomicAdd target).
__global__ void prep_kernel(const float* __restrict__ z, const float* __restrict__ W1,
                            const float* __restrict__ b2p,
                            unsigned short* __restrict__ zb, unsigned short* __restrict__ w1s,
                            float* __restrict__ outz, int nz4, int nout4) {
    int stride = gridDim.x * blockDim.x;
    const int nw = 256 * 64;   // (hb*16+kst) x lane
    const int total = nz4 + nw + nout4;
    const float b2v = b2p[0];
    for (int idx = blockIdx.x * blockDim.x + threadIdx.x; idx < total; idx += stride) {
        if (idx < nz4) {
            float4 v = ((const float4*)z)[idx];
            ushort4 o;
            o.x = f2b(v.x); o.y = f2b(v.y); o.z = f2b(v.z); o.w = f2b(v.w);
            ((ushort4*)zb)[idx] = o;
        } else if (idx < nz4 + nw) {
            int u = idx - nz4;            // 0..16383
            int lane = u & 63;
            int blk  = u >> 6;            // hb*16 + kst
            int h  = (blk >> 4) * 32 + (lane & 31);
            int kb = (blk & 15) * 16 + (lane >> 5) * 8;
            const float* src = W1 + h * 256 + kb;
            ushort4 o0, o1;
            float4 v0 = *(const float4*)(src);
            float4 v1 = *(const float4*)(src + 4);
            o0.x = f2b(v0.x); o0.y = f2b(v0.y); o0.z = f2b(v0.z); o0.w = f2b(v0.w);
            o1.x = f2b(v1.x); o1.y = f2b(v1.y); o1.z = f2b(v1.z); o1.w = f2b(v1.w);
            ushort4* dst = (ushort4*)(w1s + u * 8);
            dst[0] = o0; dst[1] = o1;
        } else {
            ((float4*)outz)[idx - nz4 - nw] = (float4){b2v, b2v, b2v, b2v};
        }
    }
}

__global__ __launch_bounds__(512, 2)
void edge_mlp_kernel(const int* __restrict__ ei, const unsigned short* __restrict__ zb,
                     const unsigned short* __restrict__ w1s,
                     const float* __restrict__ b1, const float* __restrict__ W2,
                     float* __restrict__ out, int E, int ntiles) {
    __shared__ unsigned short ldsA[4][64 * 256];  // 128 KB: quad-buffered A tiles
    __shared__ float ldsB1[512];                  // 2 KB staged b1
    __shared__ float ldsW2[512];                  // 2 KB staged W2

    const int tid  = threadIdx.x;
    const int lane = tid & 63;
    const int w    = tid >> 6;        // 0..7 : 64-h slice of H=512
    const int l31  = lane & 31;
    const int hi   = lane >> 5;       // 0/1 : k-half within frag, C row-group
    const int G    = gridDim.x;
    const int t0   = blockIdx.x;
    if (t0 >= ntiles) return;

    ldsB1[tid] = b1[tid];
    ldsW2[tid] = W2[tid];

    // ---- persistent W1: wave w holds hb w*2, w*2+1 (64 h), in regs ----
    uint4 breg[2][16];                // 128 regs
    #pragma unroll
    for (int j = 0; j < 2; ++j)
        #pragma unroll
        for (int kst = 0; kst < 16; ++kst)
            breg[j][kst] = *(const uint4*)(w1s + (((w * 2 + j) * 16 + kst) << 9) + lane * 8);

    // gather: instr q covers rows m=(w*8+q*2)+hi; lane L writes LDS slot
    // L&31 of the row pair; source k-slot pre-swizzled: side*16 + (l15^(m&7)).
    const int side = (lane >> 4) & 1;
    const int l15  = lane & 15;
    const int swz3 = (l31 & 7) << 3;  // read-side XOR on the low-4 slot bits (x8 elems)

#define ISSUE_GATHER(BUF, IV)                                                 \
    do {                                                                      \
        _Pragma("unroll")                                                     \
        for (int q_ = 0; q_ < 4; ++q_) {                                      \
            int m_   = w * 8 + q_ * 2 + hi;                                   \
            int s15_ = l15 ^ (m_ & 7);                                        \
            gload_lds16(zb + (((long)(IV)[q_]) << 7) + (s15_ << 3),           \
                        &ldsA[BUF][(w * 8 + q_ * 2) << 8]);                   \
        }                                                                     \
    } while (0)

#define LOAD_IDX(IV, T)                                                       \
    do {                                                                      \
        _Pragma("unroll")                                                     \
        for (int q_ = 0; q_ < 4; ++q_) {                                      \
            int e_ = (T) * 64 + w * 8 + q_ * 2 + hi;                          \
            e_ = (e_ < E) ? e_ : (E - 1);                                     \
            (IV)[q_] = ei[side * E + e_];                                     \
        }                                                                     \
    } while (0)

    // drain staging loads (breg/b1/W2) so the vmcnt ledger starts clean
    asm volatile("s_waitcnt vmcnt(0) lgkmcnt(0)" ::: "memory");

    // ---- prologue: idx(T0,T1) -> G_A(buf0),G_B(buf1) -> idx(T2,T3) -> pad ----
    int ivalA[4], ivalB[4];
    LOAD_IDX(ivalA, t0);
    LOAD_IDX(ivalB, t0 + G);
    ISSUE_GATHER(0, ivalA);
    ISSUE_GATHER(1, ivalB);
    asm volatile("" ::: "memory");     // pin: next idx AFTER gathers
    LOAD_IDX(ivalA, t0 + 2 * G);       // next interval's tile A
    LOAD_IDX(ivalB, t0 + 3 * G);       // next interval's tile B
    asm volatile("" ::: "memory");     // pin: pad atomics AFTER idx
    if (hi == 0) {                     // 2 queue-padding atomics (add 0.0f)
        atomicAdd(&out[t0 * 64 + l31], 0.0f);
        atomicAdd(&out[t0 * 64 + 32 + l31], 0.0f);
    }

    int p = 0;                         // buffer parity: A=p, B=p+1 (p in {0,2})
    for (int t = t0; t < ntiles; t += 2 * G) {
        // last interval's newest-10 = 8 idx + 2 atomics -> vmcnt(10)
        // completes G_A' and G_B' for this interval. One barrier per 2 tiles.
        asm volatile("s_waitcnt vmcnt(10)" ::: "memory");
        __builtin_amdgcn_s_barrier();
        asm volatile("" ::: "memory");

        const int nb = p ^ 2;          // next interval's buffer pair

        // ================= tile A = t (buffer p) =================
        {
            const unsigned short* bufc = &ldsA[p][0];
            f32x16 acc[2][2];
            #pragma unroll
            for (int j = 0; j < 2; ++j)
                #pragma unroll
                for (int q = 0; q < 4; ++q) {
                    f32x4 b = *(const f32x4*)&ldsB1[w * 64 + j * 32 + q * 8 + hi * 4];
                    #pragma unroll
                    for (int rr = 0; rr < 4; ++rr) {
                        acc[0][j][q * 4 + rr] = b[rr];
                        acc[1][j][q * 4 + rr] = b[rr];
                    }
                }

            __builtin_amdgcn_s_setprio(1);
            #pragma unroll
            for (int kst = 0; kst < 8; ++kst) {
                bf16x8 a[2];
                #pragma unroll
                for (int i = 0; i < 2; ++i) {
                    int s = kst * 2 + hi;
                    int off = ((i * 32 + l31) << 8) + ((s & 16) << 3) + (((s & 15) << 3) ^ swz3);
                    a[i] = *(const bf16x8*)&bufc[off];
                }
                #pragma unroll
                for (int i = 0; i < 2; ++i)
                    #pragma unroll
                    for (int j = 0; j < 2; ++j)
                        acc[i][j] = __builtin_amdgcn_mfma_f32_32x32x16_bf16(
                            *(const bf16x8*)&breg[j][kst], a[i], acc[i][j], 0, 0, 0);
            }
            __builtin_amdgcn_s_setprio(0);

            ISSUE_GATHER(nb, ivalA);       // mid-tile (placement load-bearing)
            asm volatile("" ::: "memory");

            __builtin_amdgcn_s_setprio(1);
            #pragma unroll
            for (int kst = 8; kst < 16; ++kst) {
                bf16x8 a[2];
                #pragma unroll
                for (int i = 0; i < 2; ++i) {
                    int s = kst * 2 + hi;
                    int off = ((i * 32 + l31) << 8) + ((s & 16) << 3) + (((s & 15) << 3) ^ swz3);
                    a[i] = *(const bf16x8*)&bufc[off];
                }
                #pragma unroll
                for (int i = 0; i < 2; ++i)
                    #pragma unroll
                    for (int j = 0; j < 2; ++j)
                        acc[i][j] = __builtin_amdgcn_mfma_f32_32x32x16_bf16(
                            *(const bf16x8*)&breg[j][kst], a[i], acc[i][j], 0, 0, 0);
            }
            __builtin_amdgcn_s_setprio(0);

            float s2[2];
            #pragma unroll
            for (int i = 0; i < 2; ++i) {
                float s = 0.f;
                #pragma unroll
                for (int j = 0; j < 2; ++j)
                    #pragma unroll
                    for (int q = 0; q < 4; ++q) {
                        f32x4 w2q = *(const f32x4*)&ldsW2[w * 64 + j * 32 + q * 8 + hi * 4];
                        #pragma unroll
                        for (int rr = 0; rr < 4; ++rr)
                            s = fmaf(fmaxf(acc[i][j][q * 4 + rr], 0.f), w2q[rr], s);
                    }
                s += __shfl_xor(s, 32);
                s2[i] = s;
            }
            #pragma unroll
            for (int i = 0; i < 2; ++i) {
                int e = t * 64 + i * 32 + l31;
                if (hi == 0 && e < E) atomicAdd(&out[e], s2[i]);
            }
        }

        // ================= tile B = t + G (buffer p+1) =================
        {
            const int tB = t + G;
            const unsigned short* bufc = &ldsA[p + 1][0];
            f32x16 acc[2][2];
            #pragma unroll
            for (int j = 0; j < 2; ++j)
                #pragma unroll
                for (int q = 0; q < 4; ++q) {
                    f32x4 b = *(const f32x4*)&ldsB1[w * 64 + j * 32 + q * 8 + hi * 4];
                    #pragma unroll
                    for (int rr = 0; rr < 4; ++rr) {
                        acc[0][j][q * 4 + rr] = b[rr];
                        acc[1][j][q * 4 + rr] = b[rr];
                    }
                }

            __builtin_amdgcn_s_setprio(1);
            #pragma unroll
            for (int kst = 0; kst < 8; ++kst) {
                bf16x8 a[2];
                #pragma unroll
                for (int i = 0; i < 2; ++i) {
                    int s = kst * 2 + hi;
                    int off = ((i * 32 + l31) << 8) + ((s & 16) << 3) + (((s & 15) << 3) ^ swz3);
                    a[i] = *(const bf16x8*)&bufc[off];
                }
                #pragma unroll
                for (int i = 0; i < 2; ++i)
                    #pragma unroll
                    for (int j = 0; j < 2; ++j)
                        acc[i][j] = __builtin_amdgcn_mfma_f32_32x32x16_bf16(
                            *(const bf16x8*)&breg[j][kst], a[i], acc[i][j], 0, 0, 0);
            }
            __builtin_amdgcn_s_setprio(0);

            ISSUE_GATHER(nb + 1, ivalB);   // mid-tile
            asm volatile("" ::: "memory"); // pin: idx reload AFTER gathers
            // FIXED (R18 bug): prefetch distance = 2 intervals ahead.
            LOAD_IDX(ivalA, t + 4 * G);
            LOAD_IDX(ivalB, t + 5 * G);
            asm volatile("" ::: "memory"); // pin: body mem ops AFTER idx

            __builtin_amdgcn_s_setprio(1);
            #pragma unroll
            for (int kst = 8; kst < 16; ++kst) {
                bf16x8 a[2];
                #pragma unroll
                for (int i = 0; i < 2; ++i) {
                    int s = kst * 2 + hi;
                    int off = ((i * 32 + l31) << 8) + ((s & 16) << 3) + (((s & 15) << 3) ^ swz3);
                    a[i] = *(const bf16x8*)&bufc[off];
                }
                #pragma unroll
                for (int i = 0; i < 2; ++i)
                    #pragma unroll
                    for (int j = 0; j < 2; ++j)
                        acc[i][j] = __builtin_amdgcn_mfma_f32_32x32x16_bf16(
                            *(const bf16x8*)&breg[j][kst], a[i], acc[i][j], 0, 0, 0);
            }
            __builtin_amdgcn_s_setprio(0);

            float s2[2];
            #pragma unroll
            for (int i = 0; i < 2; ++i) {
                float s = 0.f;
                #pragma unroll
                for (int j = 0; j < 2; ++j)
                    #pragma unroll
                    for (int q = 0; q < 4; ++q) {
                        f32x4 w2q = *(const f32x4*)&ldsW2[w * 64 + j * 32 + q * 8 + hi * 4];
                        #pragma unroll
                        for (int rr = 0; rr < 4; ++rr)
                            s = fmaf(fmaxf(acc[i][j][q * 4 + rr], 0.f), w2q[rr], s);
                    }
                s += __shfl_xor(s, 32);
                s2[i] = s;
            }
            #pragma unroll
            for (int i = 0; i < 2; ++i) {
                int e = tB * 64 + i * 32 + l31;
                if (hi == 0 && e < E) atomicAdd(&out[e], s2[i]);
            }
        }

        p ^= 2;
    }
#undef ISSUE_GATHER
#undef LOAD_IDX
}

extern "C" void kernel_launch(void* const* d_in, const int* in_sizes, int n_in,
                              void* d_out, int out_size, void* d_ws, size_t ws_size,
                              hipStream_t stream) {
    const float* z  = (const float*)d_in[0];
    const int*   ei = (const int*)d_in[1];
    const float* W1 = (const float*)d_in[2];
    const float* b1 = (const float*)d_in[3];
    const float* W2 = (const float*)d_in[4];
    const float* b2 = (const float*)d_in[5];
    float* out = (float*)d_out;

    const int E  = in_sizes[1] / 2;   // 500000
    const int NZ = in_sizes[0];       // 6400000 = N*D

    unsigned short* zb  = (unsigned short*)d_ws;       // 12.8 MB
    unsigned short* w1s = zb + NZ;                     // 256 KB (swizzled W1)

    prep_kernel<<<2048, 256, 0, stream>>>(z, W1, b2, zb, w1s, out, NZ / 4, E / 4);

    const int ntiles = (E + 63) / 64;                  // 7813
    int grid = 256;                                    // persistent, 1 block/CU
    edge_mlp_kernel<<<grid, 512, 0, stream>>>(ei, zb, w1s, b1, W2, out, E, ntiles);
}

// Round 13
// 193.267 us; speedup vs baseline: 1.1422x; 1.0666x over previous
//
#include <hip/hip_runtime.h>

// y[e] = W2 . relu(W1 . concat(z[src[e]], z[dst[e]]) + b1) + b2
// N=50000, D=128, H=512, E=500000. 131 GFLOP in GEMM1.
// R20: R15 base (121.6us best; R19's 2-tile barrier interval regressed ->
// barrier amortization closed) + FIXED 4-bit LDS swizzle.
// Bank forensics: read addr byte = row*512 + (s&16)*16 + ((s&15)^(l31&7))*16;
// row*512 and (s&16)*16 are = 0 mod 128B -> bank set by the XOR field only.
// 3-bit XOR (l31&7) -> 8 distinct slot positions over 32 lanes -> 4 lanes
// (same l31&7, different rows) per bank = 4-WAY CONFLICT on every A-read.
// Measured: 8.0M conflicts / 2M reads = +4 cyc/b128 (12->16, m136's 1.58x).
// Fix: XOR with 4 row bits (l31&15) on BOTH sides (write: s15_=l15^(m_&15),
// read: ^((l31&15)<<3)) -> 16 positions x 2 rows-16-apart = 2-way = free.
// Earlier "conflicts are gather-write inherent" was wrong (R10/R17 note).
// Kept verbatim from R15: persistent blocks (grid=256), W1-in-regs
// (128/wave), 32x32x16 operand-swapped MFMA (C row=h col=edge), MID-tile
// gather issue (load-bearing, 2x confirmed), b1 acc-init from LDS, w2 from
// LDS epilogue, atomic epilogue into b2-prefilled out, single barrier +
// vmcnt(6) ledger per tile ([4 G][4 idx][2 atomics]).

typedef __bf16 bf16x8 __attribute__((ext_vector_type(8)));
typedef float f32x4  __attribute__((ext_vector_type(4)));
typedef float f32x16 __attribute__((ext_vector_type(16)));

__device__ __forceinline__ unsigned short f2b(float f) {
    unsigned int u = __float_as_uint(f);
    u = (u + 0x7fffu + ((u >> 16) & 1u)) >> 16;   // RNE
    return (unsigned short)u;
}

__device__ __forceinline__ void gload_lds16(const unsigned short* g, unsigned short* l) {
    __builtin_amdgcn_global_load_lds(
        (const __attribute__((address_space(1))) unsigned int*)g,
        (__attribute__((address_space(3))) unsigned int*)l, 16, 0, 0);
}

// zb: z as bf16 [N][128].  w1s: W1 in 32x32x16 A-fragment order:
// w1s[(hb*16 + kst)*512 + lane*8 + t]
//   = bf16(W1[hb*32 + (lane&31)][kst*16 + (lane>>5)*8 + t]),  hb,kst in 0..15
// Also pre-fills out[] with b2 (atomicAdd target).
__global__ void prep_kernel(const float* __restrict__ z, const float* __restrict__ W1,
                            const float* __restrict__ b2p,
                            unsigned short* __restrict__ zb, unsigned short* __restrict__ w1s,
                            float* __restrict__ outz, int nz4, int nout4) {
    int stride = gridDim.x * blockDim.x;
    const int nw = 256 * 64;   // (hb*16+kst) x lane
    const int total = nz4 + nw + nout4;
    const float b2v = b2p[0];
    for (int idx = blockIdx.x * blockDim.x + threadIdx.x; idx < total; idx += stride) {
        if (idx < nz4) {
            float4 v = ((const float4*)z)[idx];
            ushort4 o;
            o.x = f2b(v.x); o.y = f2b(v.y); o.z = f2b(v.z); o.w = f2b(v.w);
            ((ushort4*)zb)[idx] = o;
        } else if (idx < nz4 + nw) {
            int u = idx - nz4;            // 0..16383
            int lane = u & 63;
            int blk  = u >> 6;            // hb*16 + kst
            int h  = (blk >> 4) * 32 + (lane & 31);
            int kb = (blk & 15) * 16 + (lane >> 5) * 8;
            const float* src = W1 + h * 256 + kb;
            ushort4 o0, o1;
            float4 v0 = *(const float4*)(src);
            float4 v1 = *(const float4*)(src + 4);
            o0.x = f2b(v0.x); o0.y = f2b(v0.y); o0.z = f2b(v0.z); o0.w = f2b(v0.w);
            o1.x = f2b(v1.x); o1.y = f2b(v1.y); o1.z = f2b(v1.z); o1.w = f2b(v1.w);
            ushort4* dst = (ushort4*)(w1s + u * 8);
            dst[0] = o0; dst[1] = o1;
        } else {
            ((float4*)outz)[idx - nz4 - nw] = (float4){b2v, b2v, b2v, b2v};
        }
    }
}

__global__ __launch_bounds__(512, 2)
void edge_mlp_kernel(const int* __restrict__ ei, const unsigned short* __restrict__ zb,
                     const unsigned short* __restrict__ w1s,
                     const float* __restrict__ b1, const float* __restrict__ W2,
                     float* __restrict__ out, int E, int ntiles) {
    __shared__ unsigned short ldsA[2][64 * 256];  // 64 KB, dbuf A tiles
    __shared__ float ldsB1[512];                  // 2 KB staged b1
    __shared__ float ldsW2[512];                  // 2 KB staged W2

    const int tid  = threadIdx.x;
    const int lane = tid & 63;
    const int w    = tid >> 6;        // 0..7 : 64-h slice of H=512
    const int l31  = lane & 31;
    const int hi   = lane >> 5;       // 0/1 : k-half within frag, C row-group
    const int G    = gridDim.x;
    const int t0   = blockIdx.x;
    if (t0 >= ntiles) return;

    ldsB1[tid] = b1[tid];
    ldsW2[tid] = W2[tid];

    // ---- persistent W1: wave w holds hb w*2, w*2+1 (64 h), in regs ----
    uint4 breg[2][16];                // 128 regs
    #pragma unroll
    for (int j = 0; j < 2; ++j)
        #pragma unroll
        for (int kst = 0; kst < 16; ++kst)
            breg[j][kst] = *(const uint4*)(w1s + (((w * 2 + j) * 16 + kst) << 9) + lane * 8);

    // gather: instr q covers rows m=(w*8+q*2)+hi; lane L writes LDS slot
    // L&31 of the row pair; source k-slot pre-swizzled s15 = l15 ^ (m&15)
    // (4-bit row XOR -> read side 2-way max = free).
    const int side = (lane >> 4) & 1;
    const int l15  = lane & 15;
    const int swz4 = (l31 & 15) << 3; // read-side XOR on the low-4 slot bits (x8 elems)

#define ISSUE_GATHER(BUF)                                                     \
    do {                                                                      \
        _Pragma("unroll")                                                     \
        for (int q_ = 0; q_ < 4; ++q_) {                                      \
            int m_   = w * 8 + q_ * 2 + hi;                                   \
            int s15_ = l15 ^ (m_ & 15);                                       \
            gload_lds16(zb + (((long)ival[q_]) << 7) + (s15_ << 3),           \
                        &ldsA[BUF][(w * 8 + q_ * 2) << 8]);                   \
        }                                                                     \
    } while (0)

    // drain staging loads (breg/b1/W2) so the vmcnt ledger starts clean
    asm volatile("s_waitcnt vmcnt(0) lgkmcnt(0)" ::: "memory");

    // ---- prologue: idx(T0) -> gather(T0) -> idx(T1) -> 2 zero-atomics ----
    int ival[4];
    #pragma unroll
    for (int q = 0; q < 4; ++q) {
        int e = t0 * 64 + w * 8 + q * 2 + hi;
        e = (e < E) ? e : (E - 1);
        ival[q] = ei[side * E + e];
    }
    ISSUE_GATHER(0);
    asm volatile("" ::: "memory");     // pin: idx(T1) stays AFTER gathers
    {
        int t1 = t0 + G;
        #pragma unroll
        for (int q = 0; q < 4; ++q) {
            int e = t1 * 64 + w * 8 + q * 2 + hi;
            e = (e < E) ? e : (E - 1);
            ival[q] = ei[side * E + e];
        }
    }
    asm volatile("" ::: "memory");     // pin: zero-atomics AFTER idx(T1)
    if (hi == 0) {                     // 2 queue-padding atomics (add 0.0f)
        atomicAdd(&out[t0 * 64 + l31], 0.0f);
        atomicAdd(&out[t0 * 64 + 32 + l31], 0.0f);
    }

    int cur = 0;
    for (int t = t0; t < ntiles; t += G) {
        // own 4 gathers are oldest; 4 idx + 2 atomics are newer -> vmcnt(6)
        asm volatile("s_waitcnt vmcnt(6)" ::: "memory");
        __builtin_amdgcn_s_barrier();
        asm volatile("" ::: "memory");

        const unsigned short* bufc = &ldsA[cur][0];

        // acc init = b1 (acc ends as W1.x + b1); C row=h, col=edge
        // h(j,reg) = w*64 + j*32 + (reg&3) + 8*(reg>>2) + 4*hi
        f32x16 acc[2][2];                 // [edge-blk i][h-blk j]
        #pragma unroll
        for (int j = 0; j < 2; ++j)
            #pragma unroll
            for (int q = 0; q < 4; ++q) {
                f32x4 b = *(const f32x4*)&ldsB1[w * 64 + j * 32 + q * 8 + hi * 4];
                #pragma unroll
                for (int rr = 0; rr < 4; ++rr) {
                    acc[0][j][q * 4 + rr] = b[rr];
                    acc[1][j][q * 4 + rr] = b[rr];
                }
            }

        __builtin_amdgcn_s_setprio(1);
        #pragma unroll
        for (int kst = 0; kst < 8; ++kst) {
            bf16x8 a[2];
            #pragma unroll
            for (int i = 0; i < 2; ++i) {
                int s = kst * 2 + hi;     // logical 16B k-slot 0..31
                int off = ((i * 32 + l31) << 8) + ((s & 16) << 3) + (((s & 15) << 3) ^ swz4);
                a[i] = *(const bf16x8*)&bufc[off];
            }
            #pragma unroll
            for (int i = 0; i < 2; ++i)
                #pragma unroll
                for (int j = 0; j < 2; ++j)
                    acc[i][j] = __builtin_amdgcn_mfma_f32_32x32x16_bf16(
                        *(const bf16x8*)&breg[j][kst], a[i], acc[i][j], 0, 0, 0);
        }
        __builtin_amdgcn_s_setprio(0);

        // issue next tile's gathers (HBM latency hides under kst 8..15)
        ISSUE_GATHER(cur ^ 1);
        asm volatile("" ::: "memory");

        __builtin_amdgcn_s_setprio(1);
        #pragma unroll
        for (int kst = 8; kst < 16; ++kst) {
            bf16x8 a[2];
            #pragma unroll
            for (int i = 0; i < 2; ++i) {
                int s = kst * 2 + hi;
                int off = ((i * 32 + l31) << 8) + ((s & 16) << 3) + (((s & 15) << 3) ^ swz4);
                a[i] = *(const bf16x8*)&bufc[off];
            }
            #pragma unroll
            for (int i = 0; i < 2; ++i)
                #pragma unroll
                for (int j = 0; j < 2; ++j)
                    acc[i][j] = __builtin_amdgcn_mfma_f32_32x32x16_bf16(
                        *(const bf16x8*)&breg[j][kst], a[i], acc[i][j], 0, 0, 0);
        }
        __builtin_amdgcn_s_setprio(0);

        // tail: idx for tile t+2G (consumed by NEXT iter's gather-issue)
        {
            int tt = t + 2 * G;
            #pragma unroll
            for (int q = 0; q < 4; ++q) {
                int e = tt * 64 + w * 8 + q * 2 + hi;
                e = (e < E) ? e : (E - 1);
                ival[q] = ei[side * E + e];
            }
        }
        asm volatile("" ::: "memory");  // pin: epilogue atomics AFTER idx

        // epilogue: y-partial = sum_{h in slice} relu(acc)*w2 ;
        // in-reg over (j,reg) + 1 shuffle (xor32); 2 atomics (hi==0 lanes)
        float s2[2];
        #pragma unroll
        for (int i = 0; i < 2; ++i) {
            float s = 0.f;
            #pragma unroll
            for (int j = 0; j < 2; ++j)
                #pragma unroll
                for (int q = 0; q < 4; ++q) {
                    f32x4 w2q = *(const f32x4*)&ldsW2[w * 64 + j * 32 + q * 8 + hi * 4];
                    #pragma unroll
                    for (int rr = 0; rr < 4; ++rr)
                        s = fmaf(fmaxf(acc[i][j][q * 4 + rr], 0.f), w2q[rr], s);
                }
            s += __shfl_xor(s, 32);
            s2[i] = s;
        }
        #pragma unroll
        for (int i = 0; i < 2; ++i) {
            int e = t * 64 + i * 32 + l31;
            if (hi == 0 && e < E) atomicAdd(&out[e], s2[i]);
        }

        cur ^= 1;
    }
#undef ISSUE_GATHER
}

extern "C" void kernel_launch(void* const* d_in, const int* in_sizes, int n_in,
                              void* d_out, int out_size, void* d_ws, size_t ws_size,
                              hipStream_t stream) {
    const float* z  = (const float*)d_in[0];
    const int*   ei = (const int*)d_in[1];
    const float* W1 = (const float*)d_in[2];
    const float* b1 = (const float*)d_in[3];
    const float* W2 = (const float*)d_in[4];
    const float* b2 = (const float*)d_in[5];
    float* out = (float*)d_out;

    const int E  = in_sizes[1] / 2;   // 500000
    const int NZ = in_sizes[0];       // 6400000 = N*D

    unsigned short* zb  = (unsigned short*)d_ws;       // 12.8 MB
    unsigned short* w1s = zb + NZ;                     // 256 KB (swizzled W1)

    prep_kernel<<<2048, 256, 0, stream>>>(z, W1, b2, zb, w1s, out, NZ / 4, E / 4);

    const int ntiles = (E + 63) / 64;                  // 7813
    int grid = 256;                                    // persistent, 1 block/CU
    edge_mlp_kernel<<<grid, 512, 0, stream>>>(ei, zb, w1s, b1, W2, out, E, ntiles);
}